// Round 9
// baseline (114.071 us; speedup 1.0000x reference)
//
#include <hip/hip_runtime.h>
#include <hip/hip_bf16.h>
#include <stdint.h>

#define L_ 128
#define B_ 4
#define H_ 768
#define R_ 97
#define LN_EPS 1e-5f

typedef _Float16 f16x8 __attribute__((ext_vector_type(8)));
typedef _Float16 f16x4 __attribute__((ext_vector_type(4)));
typedef _Float16 f16x2 __attribute__((ext_vector_type(2)));
typedef float f32x4 __attribute__((ext_vector_type(4)));

// ================= merged prep: cc-concat, Bp pack, WoP pack, gamma/beta f16, gmax zero =====
// fragment layout for B operands: half index f = ((ks*NT + nt)*64 + l)*8 + j
// where lane l holds col n = nt*16 + (l&15), k = ks*32 + (l>>4)*8 + j.
__global__ __launch_bounds__(256) void prep_all(const float* __restrict__ h1,
                                                const float* __restrict__ h2,
                                                const float* __restrict__ Wr,
                                                const float* __restrict__ Wh,
                                                const float* __restrict__ Wo,
                                                const float* __restrict__ gamma,
                                                const float* __restrict__ beta,
                                                _Float16* __restrict__ ccH,
                                                _Float16* __restrict__ Bp,
                                                _Float16* __restrict__ WoP,
                                                _Float16* __restrict__ gbH,
                                                unsigned int* __restrict__ gmaxU) {
  int blk = blockIdx.x;
  if (blk < 512) {                          // ---- concat h1|h2 -> f16 [512][1536]
    const float2* s1 = (const float2*)(h1 + (size_t)blk * H_);
    const float2* s2 = (const float2*)(h2 + (size_t)blk * H_);
    f16x2* d = (f16x2*)(ccH + (size_t)blk * (2 * H_));
    for (int i = threadIdx.x; i < H_ / 2; i += 256) {
      float2 v = s1[i]; f16x2 o; o[0] = (_Float16)v.x; o[1] = (_Float16)v.y; d[i] = o;
    }
    for (int i = threadIdx.x; i < H_ / 2; i += 256) {
      float2 v = s2[i]; f16x2 o; o[0] = (_Float16)v.x; o[1] = (_Float16)v.y; d[H_ / 2 + i] = o;
    }
    return;
  }
  blk -= 512;
  if (blk < 6912) {                         // ---- pack [Wr^T | W1^T(pad) | W2^T(pad)], NT=144
    int f = (blk * 256 + threadIdx.x) * 2;
    int j = f & 7;
    int u = f >> 3;
    int lidx = u & 63; u >>= 6;
    int nt = u % 144;
    int ks = u / 144;
    int k = ks * 32 + (lidx >> 4) * 8 + j;
    int n = nt * 16 + (lidx & 15);
    float v0, v1;
    if (n < 768) {
      v0 = Wr[(size_t)n * 1536 + k];
      v1 = Wr[(size_t)n * 1536 + k + 1];
    } else if (n < 1536) {
      int n2 = n - 768;
      if (k >= 768) { v0 = Wh[(size_t)n2 * 2304 + (k - 768)]; v1 = Wh[(size_t)n2 * 2304 + (k - 767)]; }
      else { v0 = 0.f; v1 = 0.f; }
    } else {
      int n2 = n - 1536;
      if (k >= 768) { v0 = Wh[(size_t)n2 * 2304 + 768 + (k - 768)]; v1 = Wh[(size_t)n2 * 2304 + 768 + (k - 767)]; }
      else { v0 = 0.f; v1 = 0.f; }
    }
    f16x2 o; o[0] = (_Float16)v0; o[1] = (_Float16)v1;
    *(f16x2*)(Bp + f) = o;
    return;
  }
  blk -= 6912;
  if (blk < 192) {                          // ---- pack Wo [97x768] -> frags, N pad 128, NT=8
    int f = (blk * 256 + threadIdx.x) * 2;
    int j = f & 7;
    int u = f >> 3;
    int lidx = u & 63; u >>= 6;
    int nt = u & 7;
    int ks = u >> 3;
    int k = ks * 32 + (lidx >> 4) * 8 + j;
    int n = nt * 16 + (lidx & 15);
    float v0 = 0.f, v1 = 0.f;
    if (n < R_) { v0 = Wo[(size_t)n * H_ + k]; v1 = Wo[(size_t)n * H_ + k + 1]; }
    f16x2 o; o[0] = (_Float16)v0; o[1] = (_Float16)v1;
    *(f16x2*)(WoP + f) = o;
    return;
  }
  blk -= 192;
  if (blk < 3) {                            // ---- gamma/beta -> f16 (3 blocks)
    int i = blk * 256 + threadIdx.x;
    if (i < H_) {
      gbH[i] = (_Float16)gamma[i];
      gbH[H_ + i] = (_Float16)beta[i];
    }
    return;
  }
  blk -= 3;                                 // ---- zero gmaxU (12 blocks, 3072 u32)
  int i = blk * 256 + threadIdx.x;
  if (i < B_ * H_) gmaxU[i] = 0u;
}

// ================= big MFMA GEMM: [512][2304] = ccH * Bp; tile 32x64, 576 blocks =======
// epilogue: col<768 -> tanh(+br)+1 atomicMax (uint trick); else aH / bH f16.
__global__ __launch_bounds__(256) void gemm_big(const _Float16* __restrict__ A,
                                                const _Float16* __restrict__ Bp,
                                                const float* __restrict__ br,
                                                unsigned int* __restrict__ gmaxU,
                                                _Float16* __restrict__ aH,
                                                _Float16* __restrict__ bH) {
  int w = threadIdx.x >> 6, l = threadIdx.x & 63;
  int nb = blockIdx.x, mb = blockIdx.y;
  int row0 = mb * 32 + (w & 1) * 16;
  int nt0 = nb * 4 + (w >> 1) * 2;
  const f16x8* ap = (const f16x8*)(A + (size_t)(row0 + (l & 15)) * 1536 + (l >> 4) * 8);
  const f16x8* bp = (const f16x8*)(Bp + ((size_t)nt0 * 64 + l) * 8);
  // strides in f16x8 units: A per-ks = 4; B per-ks = 144*64 = 9216; B per-nt = 64.
  f32x4 acc0 = {}, acc1 = {};
  f16x8 ac = ap[0], b0c = bp[0], b1c = bp[64];
  for (int ks = 0; ks < 48; ++ks) {
    f16x8 an = {}, b0n = {}, b1n = {};
    if (ks < 47) {
      an = ap[(ks + 1) * 4];
      b0n = bp[(size_t)(ks + 1) * 9216];
      b1n = bp[(size_t)(ks + 1) * 9216 + 64];
    }
    acc0 = __builtin_amdgcn_mfma_f32_16x16x32_f16(ac, b0c, acc0, 0, 0, 0);
    acc1 = __builtin_amdgcn_mfma_f32_16x16x32_f16(ac, b1c, acc1, 0, 0, 0);
    ac = an; b0c = b0n; b1c = b1n;
  }
#pragma unroll
  for (int q = 0; q < 2; ++q) {
    f32x4 acc = q ? acc1 : acc0;
    int col = nb * 64 + (w >> 1) * 32 + q * 16 + (l & 15);
#pragma unroll
    for (int r = 0; r < 4; ++r) {
      int row = row0 + (l >> 4) * 4 + r;
      float v = acc[r];
      if (col < 768) {
        float t = tanhf(v + br[col]) + 1.0f;   // >0 => uint-monotone
        atomicMax(&gmaxU[(row & 3) * H_ + col], __float_as_uint(t));
      } else if (col < 1536) {
        aH[(size_t)row * H_ + (col - 768)] = (_Float16)v;
      } else {
        bH[(size_t)row * H_ + (col - 1536)] = (_Float16)v;
      }
    }
  }
}

// ================= gp[b][n] = dot(gmax[b,:], Wh[n,1536:2304]) + bh[n] =================
__global__ __launch_bounds__(256) void gp_kernel(const float* __restrict__ Wh,
                                                 const unsigned int* __restrict__ gmaxU,
                                                 const float* __restrict__ bh,
                                                 float* __restrict__ gpv) {
  int n = blockIdx.x;
  int w = threadIdx.x >> 6, l = threadIdx.x & 63;
  const float* wr = Wh + (size_t)n * 2304 + 1536;
  const unsigned int* gm = gmaxU + (size_t)w * H_;
  float s = 0.f;
#pragma unroll
  for (int t = 0; t < 12; ++t) {
    int i = l + 64 * t;
    s += wr[i] * (__uint_as_float(gm[i]) - 1.0f);
  }
#pragma unroll
  for (int off = 32; off; off >>= 1) s += __shfl_xor(s, off);
  if (l == 0) gpv[(size_t)w * H_ + n] = s + bh[n];
}

// ================= stats: aH2 = f16(aH + gp); S,Q per row for aH2 (0..511) and bH (512..1023)
__global__ __launch_bounds__(256) void stats(const _Float16* __restrict__ aH,
                                             const _Float16* __restrict__ bH,
                                             const float* __restrict__ gpv,
                                             _Float16* __restrict__ aH2,
                                             float* __restrict__ S,
                                             float* __restrict__ Q) {
  int r = blockIdx.x * 4 + (threadIdx.x >> 6);
  int l = threadIdx.x & 63;
  float s = 0.f, q = 0.f;
  if (r < 512) {
    int b = r & 3;
    const f16x4* ap = (const f16x4*)(aH + (size_t)r * H_);
    const float4* gp4 = (const float4*)(gpv + (size_t)b * H_);
    f16x4* op = (f16x4*)(aH2 + (size_t)r * H_);
#pragma unroll
    for (int t = 0; t < 3; ++t) {
      int i = t * 64 + l;
      f16x4 av = ap[i];
      float4 g4 = gp4[i];
      f16x4 o;
      o[0] = (_Float16)((float)av[0] + g4.x);
      o[1] = (_Float16)((float)av[1] + g4.y);
      o[2] = (_Float16)((float)av[2] + g4.z);
      o[3] = (_Float16)((float)av[3] + g4.w);
      op[i] = o;
#pragma unroll
      for (int j = 0; j < 4; ++j) { float y = (float)o[j]; s += y; q += y * y; }
    }
  } else {
    const f16x4* bp = (const f16x4*)(bH + (size_t)(r - 512) * H_);
#pragma unroll
    for (int t = 0; t < 3; ++t) {
      f16x4 bv = bp[t * 64 + l];
#pragma unroll
      for (int j = 0; j < 4; ++j) { float y = (float)bv[j]; s += y; q += y * y; }
    }
  }
#pragma unroll
  for (int off = 32; off; off >>= 1) {
    s += __shfl_xor(s, off);
    q += __shfl_xor(q, off);
  }
  if (l == 0) { S[r] = s; Q[r] = q; }
}

// ================= dotab: cross dot -> mu/rs per (k,l,b) row via MFMA ===================
// grid (2 ltq, 8 kt, 4 b), 4 waves: wave w -> l-tile lt = ltq*4+w (16 cols), 16 k-rows.
// K = H_ = 768 -> 24 k-steps of 32.
__global__ __launch_bounds__(256) void dotab(const _Float16* __restrict__ aH2,
                                             const _Float16* __restrict__ bH,
                                             const float* __restrict__ S,
                                             const float* __restrict__ Q,
                                             float* __restrict__ mu_arr,
                                             float* __restrict__ rs_arr) {
  int w = threadIdx.x >> 6, l = threadIdx.x & 63;
  int ltq = blockIdx.x, kt = blockIdx.y, b = blockIdx.z;
  int lt = ltq * 4 + w;
  const f16x8* ap = (const f16x8*)(aH2 + ((size_t)(kt * 16 + (l & 15)) * 4 + b) * H_ + (l >> 4) * 8);
  const f16x8* bp = (const f16x8*)(bH + ((size_t)(lt * 16 + (l & 15)) * 4 + b) * H_ + (l >> 4) * 8);
  f32x4 acc = {};
  f16x8 a0 = ap[0], b0 = bp[0], a1 = ap[4], b1 = bp[4];
  for (int ks = 0; ks < 24; ++ks) {
    f16x8 a2 = {}, b2 = {};
    if (ks < 22) { a2 = ap[(ks + 2) * 4]; b2 = bp[(ks + 2) * 4]; }
    acc = __builtin_amdgcn_mfma_f32_16x16x32_f16(a0, b0, acc, 0, 0, 0);
    a0 = a1; b0 = b1; a1 = a2; b1 = b2;
  }
#pragma unroll
  for (int r = 0; r < 4; ++r) {
    int k = kt * 16 + (l >> 4) * 4 + r;
    int lg = lt * 16 + (l & 15);
    int arow = k * 4 + b, brow = lg * 4 + b;
    float mu = (S[arow] + S[512 + brow]) * (1.f / H_);
    float q2 = Q[arow] + Q[512 + brow] + 2.f * acc[r];
    float var = fmaxf(q2 * (1.f / H_) - mu * mu, 0.f);   // guard: true var >= 0
    float rs = rsqrtf(var + LN_EPS);
    size_t idx = (size_t)k * 512 + (size_t)lg * 4 + b;
    mu_arr[idx] = mu;
    rs_arr[idx] = rs;
  }
}

// ================= fused: K-split 8-wave blocks, barrier-free inner loop ================
// Block = 512 threads / 8 waves: wave (rg = w&3, kh = w>>2) computes row-group rg
// (16 rows of the block's 64) over K-half kh (12 of 24 k-steps), r8-style (Wo frags
// straight from L1/L2, zero barriers in the loop). kh=1 dumps partials to LDS (28KB),
// one __syncthreads, kh=0 adds + epilogue. Doubles waves/CU (TLP) at identical
// arithmetic — attacks the 37-50% VALUBusy duty-cycle seen in r5/r8.
__global__ __launch_bounds__(512) void fused2(const _Float16* __restrict__ aH2,
                                              const _Float16* __restrict__ bH,
                                              const _Float16* __restrict__ gbH,
                                              const _Float16* __restrict__ WoP,
                                              const float* __restrict__ bo,
                                              const float* __restrict__ mask,
                                              const float* __restrict__ mu_arr,
                                              const float* __restrict__ rs_arr,
                                              float* __restrict__ out) {
  __shared__ __align__(16) float accLds[4 * 7 * 256];   // 28 KB
  int tid = threadIdx.x, w = tid >> 6, l = tid & 63;
  int rg = w & 3, kh = w >> 2;
  int m0 = blockIdx.x * 64;
  int myrow = m0 + rg * 16 + (l & 15);
  int b = myrow & 3, li = (myrow >> 2) & 127, kk = myrow >> 9;
  const f16x8* ap = (const f16x8*)(aH2 + ((size_t)kk * 4 + b) * H_ + (l >> 4) * 8);
  const f16x8* bp = (const f16x8*)(bH + ((size_t)li * 4 + b) * H_ + (l >> 4) * 8);
  const f16x8* gp8 = (const f16x8*)(gbH + (l >> 4) * 8);
  const f16x8* be8 = (const f16x8*)(gbH + H_ + (l >> 4) * 8);
  const f16x8* wop8 = (const f16x8*)WoP;    // frag q of k-step ks at [ks*512 + q*64 + l]
  float mu = mu_arr[myrow], rs = rs_arr[myrow];

  f32x4 acc[7] = {};
  int ks0 = kh * 12, ks1 = ks0 + 12;
  for (int ks = ks0; ks < ks1; ++ks) {
    // ---- issue the 7 B-frag loads first (coalesced 1KB each, L1/L2-hit) ----
    f16x8 bv[7];
#pragma unroll
    for (int q = 0; q < 7; ++q) bv[q] = wop8[ks * 512 + q * 64 + l];
    // ---- build A-fragment while loads fly: x = a+b; y = (x-mu)*rs*gamma + beta; elu ----
    f16x8 a8 = ap[ks * 4];
    f16x8 b8 = bp[ks * 4];
    f16x8 g8 = gp8[ks * 4];
    f16x8 e8 = be8[ks * 4];
    f16x8 av;
#pragma unroll
    for (int j = 0; j < 8; ++j) {
      float x = (float)a8[j] + (float)b8[j];
      float t = rs * (float)g8[j];
      float y = (x - mu) * t + (float)e8[j];
      float e = __expf(y) - 1.f;
      y = y > 0.f ? y : e;
      av[j] = (_Float16)y;
    }
#pragma unroll
    for (int q = 0; q < 7; ++q) {
      acc[q] = __builtin_amdgcn_mfma_f32_16x16x32_f16(av, bv[q], acc[q], 0, 0, 0);
    }
  }
  // ---- K-half combine via LDS ----
  if (kh == 1) {
#pragma unroll
    for (int q = 0; q < 7; ++q) {
      *(f32x4*)&accLds[rg * 1792 + q * 256 + l * 4] = acc[q];
    }
  }
  __syncthreads();
  if (kh == 1) return;
#pragma unroll
  for (int q = 0; q < 7; ++q) {
    f32x4 o = *(const f32x4*)&accLds[rg * 1792 + q * 256 + l * 4];
    acc[q] += o;
  }
  // ---- epilogue: bias, sigmoid, mask ----
  float mv[4];
#pragma unroll
  for (int r = 0; r < 4; ++r) {
    int row = m0 + rg * 16 + (l >> 4) * 4 + r;
    int bb = row & 3, ll = (row >> 2) & 127, kx = row >> 9;
    mv[r] = mask[kx * 4 + bb] * mask[ll * 4 + bb];
  }
#pragma unroll
  for (int q = 0; q < 7; ++q) {
    int col = q * 16 + (l & 15);
    if (col < R_) {
      float bov = bo[col];
#pragma unroll
      for (int r = 0; r < 4; ++r) {
        int row = m0 + rg * 16 + (l >> 4) * 4 + r;
        float z = acc[q][r] + bov;
        out[(size_t)row * R_ + col] = mv[r] / (1.f + __expf(-z));
      }
    }
  }
}

extern "C" void kernel_launch(void* const* d_in, const int* in_sizes, int n_in,
                              void* d_out, int out_size, void* d_ws, size_t ws_size,
                              hipStream_t stream) {
  const float* h1    = (const float*)d_in[0];
  const float* h2    = (const float*)d_in[1];
  const float* mask  = (const float*)d_in[2];
  const float* Wr    = (const float*)d_in[3];
  const float* br    = (const float*)d_in[4];
  const float* Wh    = (const float*)d_in[5];
  const float* bh    = (const float*)d_in[6];
  const float* gamma = (const float*)d_in[7];
  const float* beta  = (const float*)d_in[8];
  const float* Wo    = (const float*)d_in[9];
  const float* bo    = (const float*)d_in[10];
  float* out = (float*)d_out;
  char* ws = (char*)d_ws;

  // ws layout (bytes, 16B-aligned chunks)
  _Float16* ccH = (_Float16*)ws;                    size_t off = 512 * 1536 * 2;       // 1.5MB
  _Float16* Bp  = (_Float16*)(ws + off);            off += (size_t)1536 * 2304 * 2;    // 7MB
  _Float16* WoP = (_Float16*)(ws + off);            off += 768 * 128 * 2;              // 192KB
  _Float16* gbH = (_Float16*)(ws + off);            off += 4096;
  _Float16* aH  = (_Float16*)(ws + off);            off += 512 * 768 * 2;
  _Float16* bH  = (_Float16*)(ws + off);            off += 512 * 768 * 2;
  _Float16* aH2 = (_Float16*)(ws + off);            off += 512 * 768 * 2;
  unsigned int* gmaxU = (unsigned int*)(ws + off);  off += 3072 * 4;
  float* gpv = (float*)(ws + off);                  off += 3072 * 4;
  float* S   = (float*)(ws + off);                  off += 1024 * 4;
  float* Q   = (float*)(ws + off);                  off += 1024 * 4;
  float* mu_arr = (float*)(ws + off);               off += 65536 * 4;
  float* rs_arr = (float*)(ws + off);               off += 65536 * 4;

  prep_all<<<512 + 6912 + 192 + 3 + 12, 256, 0, stream>>>(h1, h2, Wr, Wh, Wo, gamma, beta,
                                                          ccH, Bp, WoP, gbH, gmaxU);

  gemm_big<<<dim3(36, 16), 256, 0, stream>>>(ccH, Bp, br, gmaxU, aH, bH);
  gp_kernel<<<768, 256, 0, stream>>>(Wh, gmaxU, bh, gpv);
  stats<<<256, 256, 0, stream>>>(aH, bH, gpv, aH2, S, Q);
  dotab<<<dim3(2, 8, 4), 256, 0, stream>>>(aH2, bH, S, Q, mu_arr, rs_arr);

  fused2<<<1024, 512, 0, stream>>>(aH2, bH, gbH, WoP, bo, mask, mu_arr, rs_arr, out);
}

// Round 10
// 99.428 us; speedup vs baseline: 1.1473x; 1.1473x over previous
//
#include <hip/hip_runtime.h>
#include <hip/hip_bf16.h>
#include <stdint.h>

#define L_ 128
#define B_ 4
#define H_ 768
#define R_ 97
#define LN_EPS 1e-5f

typedef _Float16 f16x8 __attribute__((ext_vector_type(8)));
typedef _Float16 f16x4 __attribute__((ext_vector_type(4)));
typedef _Float16 f16x2 __attribute__((ext_vector_type(2)));
typedef float f32x4 __attribute__((ext_vector_type(4)));

extern "C" __device__ _Float16 __ocml_exp_f16(_Float16);

// ================= merged prep: cc-concat, Bp pack, WoP pack, gamma/beta f16, gmax zero =====
// fragment layout for B operands: half index f = ((ks*NT + nt)*64 + l)*8 + j
// where lane l holds col n = nt*16 + (l&15), k = ks*32 + (l>>4)*8 + j.
__global__ __launch_bounds__(256) void prep_all(const float* __restrict__ h1,
                                                const float* __restrict__ h2,
                                                const float* __restrict__ Wr,
                                                const float* __restrict__ Wh,
                                                const float* __restrict__ Wo,
                                                const float* __restrict__ gamma,
                                                const float* __restrict__ beta,
                                                _Float16* __restrict__ ccH,
                                                _Float16* __restrict__ Bp,
                                                _Float16* __restrict__ WoP,
                                                _Float16* __restrict__ gbH,
                                                unsigned int* __restrict__ gmaxU) {
  int blk = blockIdx.x;
  if (blk < 512) {                          // ---- concat h1|h2 -> f16 [512][1536]
    const float2* s1 = (const float2*)(h1 + (size_t)blk * H_);
    const float2* s2 = (const float2*)(h2 + (size_t)blk * H_);
    f16x2* d = (f16x2*)(ccH + (size_t)blk * (2 * H_));
    for (int i = threadIdx.x; i < H_ / 2; i += 256) {
      float2 v = s1[i]; f16x2 o; o[0] = (_Float16)v.x; o[1] = (_Float16)v.y; d[i] = o;
    }
    for (int i = threadIdx.x; i < H_ / 2; i += 256) {
      float2 v = s2[i]; f16x2 o; o[0] = (_Float16)v.x; o[1] = (_Float16)v.y; d[H_ / 2 + i] = o;
    }
    return;
  }
  blk -= 512;
  if (blk < 6912) {                         // ---- pack [Wr^T | W1^T(pad) | W2^T(pad)], NT=144
    int f = (blk * 256 + threadIdx.x) * 2;
    int j = f & 7;
    int u = f >> 3;
    int lidx = u & 63; u >>= 6;
    int nt = u % 144;
    int ks = u / 144;
    int k = ks * 32 + (lidx >> 4) * 8 + j;
    int n = nt * 16 + (lidx & 15);
    float v0, v1;
    if (n < 768) {
      v0 = Wr[(size_t)n * 1536 + k];
      v1 = Wr[(size_t)n * 1536 + k + 1];
    } else if (n < 1536) {
      int n2 = n - 768;
      if (k >= 768) { v0 = Wh[(size_t)n2 * 2304 + (k - 768)]; v1 = Wh[(size_t)n2 * 2304 + (k - 767)]; }
      else { v0 = 0.f; v1 = 0.f; }
    } else {
      int n2 = n - 1536;
      if (k >= 768) { v0 = Wh[(size_t)n2 * 2304 + 768 + (k - 768)]; v1 = Wh[(size_t)n2 * 2304 + 768 + (k - 767)]; }
      else { v0 = 0.f; v1 = 0.f; }
    }
    f16x2 o; o[0] = (_Float16)v0; o[1] = (_Float16)v1;
    *(f16x2*)(Bp + f) = o;
    return;
  }
  blk -= 6912;
  if (blk < 192) {                          // ---- pack Wo [97x768] -> frags, N pad 128, NT=8
    int f = (blk * 256 + threadIdx.x) * 2;
    int j = f & 7;
    int u = f >> 3;
    int lidx = u & 63; u >>= 6;
    int nt = u & 7;
    int ks = u >> 3;
    int k = ks * 32 + (lidx >> 4) * 8 + j;
    int n = nt * 16 + (lidx & 15);
    float v0 = 0.f, v1 = 0.f;
    if (n < R_) { v0 = Wo[(size_t)n * H_ + k]; v1 = Wo[(size_t)n * H_ + k + 1]; }
    f16x2 o; o[0] = (_Float16)v0; o[1] = (_Float16)v1;
    *(f16x2*)(WoP + f) = o;
    return;
  }
  blk -= 192;
  if (blk < 3) {                            // ---- gamma/beta -> f16 (3 blocks)
    int i = blk * 256 + threadIdx.x;
    if (i < H_) {
      gbH[i] = (_Float16)gamma[i];
      gbH[H_ + i] = (_Float16)beta[i];
    }
    return;
  }
  blk -= 3;                                 // ---- zero gmaxU (12 blocks, 3072 u32)
  int i = blk * 256 + threadIdx.x;
  if (i < B_ * H_) gmaxU[i] = 0u;
}

// ================= big MFMA GEMM: [512][2304] = ccH * Bp; tile 32x64, 576 blocks =======
// epilogue: col<768 -> tanh(+br)+1 atomicMax (uint trick); else aH / bH f16.
__global__ __launch_bounds__(256) void gemm_big(const _Float16* __restrict__ A,
                                                const _Float16* __restrict__ Bp,
                                                const float* __restrict__ br,
                                                unsigned int* __restrict__ gmaxU,
                                                _Float16* __restrict__ aH,
                                                _Float16* __restrict__ bH) {
  int w = threadIdx.x >> 6, l = threadIdx.x & 63;
  int nb = blockIdx.x, mb = blockIdx.y;
  int row0 = mb * 32 + (w & 1) * 16;
  int nt0 = nb * 4 + (w >> 1) * 2;
  const f16x8* ap = (const f16x8*)(A + (size_t)(row0 + (l & 15)) * 1536 + (l >> 4) * 8);
  const f16x8* bp = (const f16x8*)(Bp + ((size_t)nt0 * 64 + l) * 8);
  // strides in f16x8 units: A per-ks = 4; B per-ks = 144*64 = 9216; B per-nt = 64.
  f32x4 acc0 = {}, acc1 = {};
  f16x8 ac = ap[0], b0c = bp[0], b1c = bp[64];
  for (int ks = 0; ks < 48; ++ks) {
    f16x8 an = {}, b0n = {}, b1n = {};
    if (ks < 47) {
      an = ap[(ks + 1) * 4];
      b0n = bp[(size_t)(ks + 1) * 9216];
      b1n = bp[(size_t)(ks + 1) * 9216 + 64];
    }
    acc0 = __builtin_amdgcn_mfma_f32_16x16x32_f16(ac, b0c, acc0, 0, 0, 0);
    acc1 = __builtin_amdgcn_mfma_f32_16x16x32_f16(ac, b1c, acc1, 0, 0, 0);
    ac = an; b0c = b0n; b1c = b1n;
  }
#pragma unroll
  for (int q = 0; q < 2; ++q) {
    f32x4 acc = q ? acc1 : acc0;
    int col = nb * 64 + (w >> 1) * 32 + q * 16 + (l & 15);
#pragma unroll
    for (int r = 0; r < 4; ++r) {
      int row = row0 + (l >> 4) * 4 + r;
      float v = acc[r];
      if (col < 768) {
        float t = tanhf(v + br[col]) + 1.0f;   // >0 => uint-monotone
        atomicMax(&gmaxU[(row & 3) * H_ + col], __float_as_uint(t));
      } else if (col < 1536) {
        aH[(size_t)row * H_ + (col - 768)] = (_Float16)v;
      } else {
        bH[(size_t)row * H_ + (col - 1536)] = (_Float16)v;
      }
    }
  }
}

// ================= gp[b][n] = dot(gmax[b,:], Wh[n,1536:2304]) + bh[n] =================
__global__ __launch_bounds__(256) void gp_kernel(const float* __restrict__ Wh,
                                                 const unsigned int* __restrict__ gmaxU,
                                                 const float* __restrict__ bh,
                                                 float* __restrict__ gpv) {
  int n = blockIdx.x;
  int w = threadIdx.x >> 6, l = threadIdx.x & 63;
  const float* wr = Wh + (size_t)n * 2304 + 1536;
  const unsigned int* gm = gmaxU + (size_t)w * H_;
  float s = 0.f;
#pragma unroll
  for (int t = 0; t < 12; ++t) {
    int i = l + 64 * t;
    s += wr[i] * (__uint_as_float(gm[i]) - 1.0f);
  }
#pragma unroll
  for (int off = 32; off; off >>= 1) s += __shfl_xor(s, off);
  if (l == 0) gpv[(size_t)w * H_ + n] = s + bh[n];
}

// ================= stats: aH2 = f16(aH + gp); S,Q per row for aH2 (0..511) and bH (512..1023)
__global__ __launch_bounds__(256) void stats(const _Float16* __restrict__ aH,
                                             const _Float16* __restrict__ bH,
                                             const float* __restrict__ gpv,
                                             _Float16* __restrict__ aH2,
                                             float* __restrict__ S,
                                             float* __restrict__ Q) {
  int r = blockIdx.x * 4 + (threadIdx.x >> 6);
  int l = threadIdx.x & 63;
  float s = 0.f, q = 0.f;
  if (r < 512) {
    int b = r & 3;
    const f16x4* ap = (const f16x4*)(aH + (size_t)r * H_);
    const float4* gp4 = (const float4*)(gpv + (size_t)b * H_);
    f16x4* op = (f16x4*)(aH2 + (size_t)r * H_);
#pragma unroll
    for (int t = 0; t < 3; ++t) {
      int i = t * 64 + l;
      f16x4 av = ap[i];
      float4 g4 = gp4[i];
      f16x4 o;
      o[0] = (_Float16)((float)av[0] + g4.x);
      o[1] = (_Float16)((float)av[1] + g4.y);
      o[2] = (_Float16)((float)av[2] + g4.z);
      o[3] = (_Float16)((float)av[3] + g4.w);
      op[i] = o;
#pragma unroll
      for (int j = 0; j < 4; ++j) { float y = (float)o[j]; s += y; q += y * y; }
    }
  } else {
    const f16x4* bp = (const f16x4*)(bH + (size_t)(r - 512) * H_);
#pragma unroll
    for (int t = 0; t < 3; ++t) {
      f16x4 bv = bp[t * 64 + l];
#pragma unroll
      for (int j = 0; j < 4; ++j) { float y = (float)bv[j]; s += y; q += y * y; }
    }
  }
#pragma unroll
  for (int off = 32; off; off >>= 1) {
    s += __shfl_xor(s, off);
    q += __shfl_xor(q, off);
  }
  if (l == 0) { S[r] = s; Q[r] = q; }
}

// ================= dotab: cross dot -> mu/rs per (k,l,b) row via MFMA ===================
// grid (2 ltq, 8 kt, 4 b), 4 waves: wave w -> l-tile lt = ltq*4+w (16 cols), 16 k-rows.
// K = H_ = 768 -> 24 k-steps of 32.
__global__ __launch_bounds__(256) void dotab(const _Float16* __restrict__ aH2,
                                             const _Float16* __restrict__ bH,
                                             const float* __restrict__ S,
                                             const float* __restrict__ Q,
                                             float* __restrict__ mu_arr,
                                             float* __restrict__ rs_arr) {
  int w = threadIdx.x >> 6, l = threadIdx.x & 63;
  int ltq = blockIdx.x, kt = blockIdx.y, b = blockIdx.z;
  int lt = ltq * 4 + w;
  const f16x8* ap = (const f16x8*)(aH2 + ((size_t)(kt * 16 + (l & 15)) * 4 + b) * H_ + (l >> 4) * 8);
  const f16x8* bp = (const f16x8*)(bH + ((size_t)(lt * 16 + (l & 15)) * 4 + b) * H_ + (l >> 4) * 8);
  f32x4 acc = {};
  f16x8 a0 = ap[0], b0 = bp[0], a1 = ap[4], b1 = bp[4];
  for (int ks = 0; ks < 24; ++ks) {
    f16x8 a2 = {}, b2 = {};
    if (ks < 22) { a2 = ap[(ks + 2) * 4]; b2 = bp[(ks + 2) * 4]; }
    acc = __builtin_amdgcn_mfma_f32_16x16x32_f16(a0, b0, acc, 0, 0, 0);
    a0 = a1; b0 = b1; a1 = a2; b1 = b2;
  }
#pragma unroll
  for (int r = 0; r < 4; ++r) {
    int k = kt * 16 + (l >> 4) * 4 + r;
    int lg = lt * 16 + (l & 15);
    int arow = k * 4 + b, brow = lg * 4 + b;
    float mu = (S[arow] + S[512 + brow]) * (1.f / H_);
    float q2 = Q[arow] + Q[512 + brow] + 2.f * acc[r];
    float var = fmaxf(q2 * (1.f / H_) - mu * mu, 0.f);   // guard: true var >= 0
    float rs = rsqrtf(var + LN_EPS);
    size_t idx = (size_t)k * 512 + (size_t)lg * 4 + b;
    mu_arr[idx] = mu;
    rs_arr[idx] = rs;
  }
}

// ================= fused: packed-f16 LN+ELU build, MFMA vs LDS-staged Wo ================
// Structure = r5/r7 proven (LDS dbuf, 2 barriers/ks, 4 waves, 7 ntiles, 51.7 µs).
// ONLY change vs r7: av-build in packed f16 (v_pk_*), ELU branchless
// max(y,0)+min(exp(y)-1,0) with v_exp_f16 — cuts ~270 VALU/wave-ks to ~100.
// (r6 deep-pipeline spilled; r8 global-Wo latency-bound; r9 K-split no help:
// the kernel is VALU-work-bound, so cut the work.)
__global__ __launch_bounds__(256) void fused2(const _Float16* __restrict__ aH2,
                                              const _Float16* __restrict__ bH,
                                              const _Float16* __restrict__ gbH,
                                              const _Float16* __restrict__ WoP,
                                              const float* __restrict__ bo,
                                              const float* __restrict__ mask,
                                              const float* __restrict__ mu_arr,
                                              const float* __restrict__ rs_arr,
                                              float* __restrict__ out) {
  __shared__ __align__(16) _Float16 WoLds[2][4096];   // 2 x 8KB (one ks-chunk)
  int tid = threadIdx.x, w = tid >> 6, l = tid & 63;
  int m0 = blockIdx.x * 64;
  int myrow = m0 + w * 16 + (l & 15);
  int b = myrow & 3, li = (myrow >> 2) & 127, kk = myrow >> 9;
  const f16x8* ap = (const f16x8*)(aH2 + ((size_t)kk * 4 + b) * H_ + (l >> 4) * 8);
  const f16x8* bp = (const f16x8*)(bH + ((size_t)li * 4 + b) * H_ + (l >> 4) * 8);
  const f16x8* gp8 = (const f16x8*)(gbH + (l >> 4) * 8);
  const f16x8* be8 = (const f16x8*)(gbH + H_ + (l >> 4) * 8);
  float mu = mu_arr[myrow], rs = rs_arr[myrow];
  _Float16 muh = (_Float16)mu, rsh = (_Float16)rs;
  f16x8 mu8, rs8, zero8, one8;
#pragma unroll
  for (int j = 0; j < 8; ++j) {
    mu8[j] = muh; rs8[j] = rsh;
    zero8[j] = (_Float16)0.f; one8[j] = (_Float16)1.f;
  }

  const uint4* wog = (const uint4*)WoP;               // 512 uint4 per ks-chunk
  uint4* lds0 = (uint4*)&WoLds[0][0];
  lds0[tid] = wog[tid];
  lds0[256 + tid] = wog[256 + tid];
  __syncthreads();

  f32x4 acc[7] = {};
  for (int ks = 0; ks < 24; ++ks) {
    int cur = ks & 1;
    uint4 wo0 = {}, wo1 = {};
    if (ks < 23) {                                     // prefetch next chunk to regs
      wo0 = wog[(ks + 1) * 512 + tid];
      wo1 = wog[(ks + 1) * 512 + 256 + tid];
    }
    // ---- packed-f16 A-fragment build: y = (a+b-mu)*rs*gamma + beta; elu ----
    f16x8 a8 = ap[ks * 4];
    f16x8 b8 = bp[ks * 4];
    f16x8 g8 = gp8[ks * 4];
    f16x8 e8 = be8[ks * 4];
    f16x8 x = a8 + b8;
    f16x8 c1 = rs8 * g8;
    f16x8 yv = (x - mu8) * c1 + e8;
    f16x8 ex;
#pragma unroll
    for (int j = 0; j < 8; ++j) ex[j] = __ocml_exp_f16(yv[j]);
    ex = ex - one8;
    f16x8 av = __builtin_elementwise_max(yv, zero8) + __builtin_elementwise_min(ex, zero8);
    __syncthreads();                     // all waves done READING buf cur^1 (prev iter)
    if (ks < 23) {
      uint4* d = (uint4*)&WoLds[cur ^ 1][0];
      d[tid] = wo0;
      d[256 + tid] = wo1;
    }
    __syncthreads();                     // writes to buf cur^1 visible before next reads
    const f16x8* bvp = (const f16x8*)&WoLds[cur][0];
#pragma unroll
    for (int q = 0; q < 7; ++q) {
      f16x8 bv = bvp[q * 64 + l];
      acc[q] = __builtin_amdgcn_mfma_f32_16x16x32_f16(av, bv, acc[q], 0, 0, 0);
    }
  }
  // ---- epilogue: bias, sigmoid, mask ----
  float mv[4];
#pragma unroll
  for (int r = 0; r < 4; ++r) {
    int row = m0 + w * 16 + (l >> 4) * 4 + r;
    int bb = row & 3, ll = (row >> 2) & 127, kx = row >> 9;
    mv[r] = mask[kx * 4 + bb] * mask[ll * 4 + bb];
  }
#pragma unroll
  for (int q = 0; q < 7; ++q) {
    int col = q * 16 + (l & 15);
    if (col < R_) {
      float bov = bo[col];
#pragma unroll
      for (int r = 0; r < 4; ++r) {
        int row = m0 + w * 16 + (l >> 4) * 4 + r;
        float z = acc[q][r] + bov;
        out[(size_t)row * R_ + col] = mv[r] / (1.f + __expf(-z));
      }
    }
  }
}

extern "C" void kernel_launch(void* const* d_in, const int* in_sizes, int n_in,
                              void* d_out, int out_size, void* d_ws, size_t ws_size,
                              hipStream_t stream) {
  const float* h1    = (const float*)d_in[0];
  const float* h2    = (const float*)d_in[1];
  const float* mask  = (const float*)d_in[2];
  const float* Wr    = (const float*)d_in[3];
  const float* br    = (const float*)d_in[4];
  const float* Wh    = (const float*)d_in[5];
  const float* bh    = (const float*)d_in[6];
  const float* gamma = (const float*)d_in[7];
  const float* beta  = (const float*)d_in[8];
  const float* Wo    = (const float*)d_in[9];
  const float* bo    = (const float*)d_in[10];
  float* out = (float*)d_out;
  char* ws = (char*)d_ws;

  // ws layout (bytes, 16B-aligned chunks)
  _Float16* ccH = (_Float16*)ws;                    size_t off = 512 * 1536 * 2;       // 1.5MB
  _Float16* Bp  = (_Float16*)(ws + off);            off += (size_t)1536 * 2304 * 2;    // 7MB
  _Float16* WoP = (_Float16*)(ws + off);            off += 768 * 128 * 2;              // 192KB
  _Float16* gbH = (_Float16*)(ws + off);            off += 4096;
  _Float16* aH  = (_Float16*)(ws + off);            off += 512 * 768 * 2;
  _Float16* bH  = (_Float16*)(ws + off);            off += 512 * 768 * 2;
  _Float16* aH2 = (_Float16*)(ws + off);            off += 512 * 768 * 2;
  unsigned int* gmaxU = (unsigned int*)(ws + off);  off += 3072 * 4;
  float* gpv = (float*)(ws + off);                  off += 3072 * 4;
  float* S   = (float*)(ws + off);                  off += 1024 * 4;
  float* Q   = (float*)(ws + off);                  off += 1024 * 4;
  float* mu_arr = (float*)(ws + off);               off += 65536 * 4;
  float* rs_arr = (float*)(ws + off);               off += 65536 * 4;

  prep_all<<<512 + 6912 + 192 + 3 + 12, 256, 0, stream>>>(h1, h2, Wr, Wh, Wo, gamma, beta,
                                                          ccH, Bp, WoP, gbH, gmaxU);

  gemm_big<<<dim3(36, 16), 256, 0, stream>>>(ccH, Bp, br, gmaxU, aH, bH);
  gp_kernel<<<768, 256, 0, stream>>>(Wh, gmaxU, bh, gpv);
  stats<<<256, 256, 0, stream>>>(aH, bH, gpv, aH2, S, Q);
  dotab<<<dim3(2, 8, 4), 256, 0, stream>>>(aH2, bH, S, Q, mu_arr, rs_arr);

  fused2<<<1024, 256, 0, stream>>>(aH2, bH, gbH, WoP, bo, mask, mu_arr, rs_arr, out);
}